// Round 1
// baseline (524.014 us; speedup 1.0000x reference)
//
#include <hip/hip_runtime.h>
#include <hip/hip_bf16.h>
#include <stdint.h>

#define E_NUM 16
#define T_NUM 8192
#define H_DIM 1024
#define I_DIM 4096
#define MPE   512   // tokens per expert

typedef __attribute__((ext_vector_type(8))) short short8;
typedef __attribute__((ext_vector_type(4))) float f32x4;
using bf16 = __hip_bfloat16;

typedef const __attribute__((address_space(1))) void GLV;
typedef __attribute__((address_space(3))) void LDSV;

// round-to-nearest-even f32 -> bf16, packed pair into one u32
__device__ __forceinline__ uint32_t pack2_bf16(float a, float b) {
  union { float f; uint32_t u; } ua, ub;
  ua.f = a; ub.f = b;
  uint32_t x = ua.u + (0x7FFFu + ((ua.u >> 16) & 1u));
  uint32_t y = ub.u + (0x7FFFu + ((ub.u >> 16) & 1u));
  return (x >> 16) | (y & 0xFFFF0000u);
}

// ---------------- gather + cast: xp[r] = bf16(hs[perm[r]]) ----------------
__global__ __launch_bounds__(256)
void gather_cast_kernel(const float* __restrict__ hs, const int* __restrict__ perm,
                        uint32_t* __restrict__ xp) {
  const int r = blockIdx.x;
  const int t = threadIdx.x;
  const int src = perm[r];
  const float4* in = (const float4*)(hs + (size_t)src * H_DIM);
  float4 v = in[t];
  uint2 o;
  o.x = pack2_bf16(v.x, v.y);
  o.y = pack2_bf16(v.z, v.w);
  ((uint2*)(xp + (size_t)r * (H_DIM / 2)))[t] = o;
}

// ---------------- grouped GEMM:  C = A(bf16,[E][512][K]) * B(f32,[E][N][K])^T ----------------
// EPI1: Hout[e][row][col] = bf16(gelu(acc + b1))       (GEMM1)
// !EPI1: Oout[perm[grow]][col] = acc + b2   (fp32)     (GEMM2, scatter)
template<bool EPI1>
__global__ __launch_bounds__(256, 2)
void moe_gemm_kernel(const bf16* __restrict__ A, const float* __restrict__ Bw,
                     const float* __restrict__ bias, bf16* __restrict__ Hout,
                     float* __restrict__ Oout, const int* __restrict__ perm,
                     const int N, const int K) {
  constexpr int BK = 64;
  __shared__ bf16 As[2][128 * BK];
  __shared__ bf16 Bs[2][128 * BK];

  const int e  = blockIdx.z;
  const int bm = blockIdx.x;   // 0..3
  const int bn = blockIdx.y;   // 0..N/128-1
  const int tid = threadIdx.x;
  const int l  = tid & 63;
  const int w  = tid >> 6;
  const int wr = w >> 1, wc = w & 1;
  const int fr = l & 15, fq = l >> 4;

  const bf16*  Ae = A  + (size_t)e * MPE * K + (size_t)bm * 128 * K;
  const float* Be = Bw + (size_t)e * N  * K + (size_t)bn * 128 * K;

  const int srow = tid >> 3;        // 0..31 (row within 32-row staging slab)
  const int scol = (tid & 7) * 8;   // 8-element chunk start along K

  f32x4 acc[4][4];
#pragma unroll
  for (int m = 0; m < 4; ++m)
#pragma unroll
    for (int n = 0; n < 4; ++n) acc[m][n] = (f32x4){0.f, 0.f, 0.f, 0.f};

  const int nk = K / BK;
  float4 breg[8];

  // ---- prologue: stage kt=0 into buffer 0
#pragma unroll
  for (int i = 0; i < 4; ++i) {
    const bf16* g = Ae + (size_t)(i * 32 + srow) * K + scol;
    __builtin_amdgcn_global_load_lds((GLV*)g, (LDSV*)&As[0][(i * 256 + w * 64) * 8], 16, 0, 0);
  }
#pragma unroll
  for (int i = 0; i < 4; ++i) {
    const float* g = Be + (size_t)(i * 32 + srow) * K + scol;
    breg[2 * i]     = *(const float4*)g;
    breg[2 * i + 1] = *(const float4*)(g + 4);
  }
#pragma unroll
  for (int i = 0; i < 4; ++i) {
    uint4 pk;
    pk.x = pack2_bf16(breg[2 * i].x,     breg[2 * i].y);
    pk.y = pack2_bf16(breg[2 * i].z,     breg[2 * i].w);
    pk.z = pack2_bf16(breg[2 * i + 1].x, breg[2 * i + 1].y);
    pk.w = pack2_bf16(breg[2 * i + 1].z, breg[2 * i + 1].w);
    *(uint4*)&Bs[0][(size_t)(i * 256 + tid) * 8] = pk;
  }
  __syncthreads();

  for (int kt = 0; kt < nk; ++kt) {
    const int cur = kt & 1;
    const int nxt = cur ^ 1;
    const bool more = (kt + 1) < nk;

    if (more) {
      const int ko = (kt + 1) * BK;
#pragma unroll
      for (int i = 0; i < 4; ++i) {
        const bf16* g = Ae + (size_t)(i * 32 + srow) * K + ko + scol;
        __builtin_amdgcn_global_load_lds((GLV*)g, (LDSV*)&As[nxt][(i * 256 + w * 64) * 8], 16, 0, 0);
      }
#pragma unroll
      for (int i = 0; i < 4; ++i) {
        const float* g = Be + (size_t)(i * 32 + srow) * K + ko + scol;
        breg[2 * i]     = *(const float4*)g;
        breg[2 * i + 1] = *(const float4*)(g + 4);
      }
    }

    // ---- compute current buffer
#pragma unroll
    for (int kk = 0; kk < 2; ++kk) {
      short8 af[4], bfv[4];
#pragma unroll
      for (int m = 0; m < 4; ++m)
        af[m] = *(const short8*)&As[cur][(wr * 64 + m * 16 + fr) * BK + kk * 32 + fq * 8];
#pragma unroll
      for (int n = 0; n < 4; ++n)
        bfv[n] = *(const short8*)&Bs[cur][(wc * 64 + n * 16 + fr) * BK + kk * 32 + fq * 8];
#pragma unroll
      for (int m = 0; m < 4; ++m)
#pragma unroll
        for (int n = 0; n < 4; ++n)
          acc[m][n] = __builtin_amdgcn_mfma_f32_16x16x32_bf16(af[m], bfv[n], acc[m][n], 0, 0, 0);
    }

    if (more) {
#pragma unroll
      for (int i = 0; i < 4; ++i) {
        uint4 pk;
        pk.x = pack2_bf16(breg[2 * i].x,     breg[2 * i].y);
        pk.y = pack2_bf16(breg[2 * i].z,     breg[2 * i].w);
        pk.z = pack2_bf16(breg[2 * i + 1].x, breg[2 * i + 1].y);
        pk.w = pack2_bf16(breg[2 * i + 1].z, breg[2 * i + 1].w);
        *(uint4*)&Bs[nxt][(size_t)(i * 256 + tid) * 8] = pk;
      }
    }
    __syncthreads();
  }

  // ---- epilogue
  float bv[4];
#pragma unroll
  for (int n = 0; n < 4; ++n)
    bv[n] = bias[(size_t)e * N + bn * 128 + wc * 64 + n * 16 + fr];

  if (EPI1) {
    bf16* He = Hout + (size_t)e * MPE * N;
#pragma unroll
    for (int m = 0; m < 4; ++m) {
#pragma unroll
      for (int j = 0; j < 4; ++j) {
        const int row = bm * 128 + wr * 64 + m * 16 + fq * 4 + j;
#pragma unroll
        for (int n = 0; n < 4; ++n) {
          const int col = bn * 128 + wc * 64 + n * 16 + fr;
          float x = acc[m][n][j] + bv[n];
          float g = 0.5f * x * (1.0f + erff(x * 0.70710678118654752f));
          He[(size_t)row * N + col] = __float2bfloat16(g);
        }
      }
    }
  } else {
#pragma unroll
    for (int m = 0; m < 4; ++m) {
#pragma unroll
      for (int j = 0; j < 4; ++j) {
        const int grow = e * MPE + bm * 128 + wr * 64 + m * 16 + fq * 4 + j;
        const int drow = perm[grow];
        float* orow = Oout + (size_t)drow * N;
#pragma unroll
        for (int n = 0; n < 4; ++n) {
          const int col = bn * 128 + wc * 64 + n * 16 + fr;
          orow[col] = acc[m][n][j] + bv[n];
        }
      }
    }
  }
}

// ---------------- residual + LayerNorm (in place on out) ----------------
__global__ __launch_bounds__(256)
void ln_resid_kernel(float* __restrict__ out, const float* __restrict__ hs,
                     const float* __restrict__ gamma, const float* __restrict__ beta) {
  const int r = blockIdx.x;
  const int t = threadIdx.x;
  float4 o = ((const float4*)(out + (size_t)r * H_DIM))[t];
  float4 h = ((const float4*)(hs  + (size_t)r * H_DIM))[t];
  float v0 = o.x + h.x, v1 = o.y + h.y, v2 = o.z + h.z, v3 = o.w + h.w;
  float s  = v0 + v1 + v2 + v3;
  float sq = v0 * v0 + v1 * v1 + v2 * v2 + v3 * v3;
#pragma unroll
  for (int off = 32; off > 0; off >>= 1) {
    s  += __shfl_down(s, off);
    sq += __shfl_down(sq, off);
  }
  __shared__ float ss[4], ssq[4];
  const int wv = t >> 6;
  if ((t & 63) == 0) { ss[wv] = s; ssq[wv] = sq; }
  __syncthreads();
  s  = ss[0] + ss[1] + ss[2] + ss[3];
  sq = ssq[0] + ssq[1] + ssq[2] + ssq[3];
  const float mu  = s * (1.0f / (float)H_DIM);
  const float var = sq * (1.0f / (float)H_DIM) - mu * mu;
  const float rs  = rsqrtf(var + 1e-12f);
  float4 g = ((const float4*)gamma)[t];
  float4 b = ((const float4*)beta)[t];
  float4 rr;
  rr.x = (v0 - mu) * rs * g.x + b.x;
  rr.y = (v1 - mu) * rs * g.y + b.y;
  rr.z = (v2 - mu) * rs * g.z + b.z;
  rr.w = (v3 - mu) * rs * g.w + b.w;
  ((float4*)(out + (size_t)r * H_DIM))[t] = rr;
}

extern "C" void kernel_launch(void* const* d_in, const int* in_sizes, int n_in,
                              void* d_out, int out_size, void* d_ws, size_t ws_size,
                              hipStream_t stream) {
  const float* hs    = (const float*)d_in[0];
  const int*   perm  = (const int*)d_in[1];
  const float* w1    = (const float*)d_in[2];
  const float* b1    = (const float*)d_in[3];
  const float* w2    = (const float*)d_in[4];
  const float* b2    = (const float*)d_in[5];
  const float* gamma = (const float*)d_in[6];
  const float* beta  = (const float*)d_in[7];
  float* out = (float*)d_out;

  // workspace: xp bf16 [T][H] = 16 MB, h bf16 [T][I] = 64 MB
  bf16* xp   = (bf16*)d_ws;
  bf16* hbuf = (bf16*)((char*)d_ws + (size_t)T_NUM * H_DIM * sizeof(bf16));

  gather_cast_kernel<<<T_NUM, 256, 0, stream>>>(hs, perm, (uint32_t*)xp);

  dim3 g1(4, I_DIM / 128, E_NUM);
  moe_gemm_kernel<true><<<g1, 256, 0, stream>>>(xp, w1, b1, hbuf, nullptr, nullptr, I_DIM, H_DIM);

  dim3 g2(4, H_DIM / 128, E_NUM);
  moe_gemm_kernel<false><<<g2, 256, 0, stream>>>(hbuf, w2, b2, nullptr, out, perm, H_DIM, I_DIM);

  ln_resid_kernel<<<T_NUM, 256, 0, stream>>>(out, hs, gamma, beta);
}

// Round 2
// 370.434 us; speedup vs baseline: 1.4146x; 1.4146x over previous
//
#include <hip/hip_runtime.h>
#include <hip/hip_bf16.h>
#include <stdint.h>

#define E_NUM 16
#define T_NUM 8192
#define H_DIM 1024
#define I_DIM 4096
#define MPE   512   // tokens per expert

typedef __attribute__((ext_vector_type(8))) short short8;
typedef __attribute__((ext_vector_type(4))) float f32x4;
using bf16 = __hip_bfloat16;

typedef const __attribute__((address_space(1))) void GLV;
typedef __attribute__((address_space(3))) void LDSV;

// round-to-nearest-even f32 -> bf16, packed pair into one u32
__device__ __forceinline__ uint32_t pack2_bf16(float a, float b) {
  union { float f; uint32_t u; } ua, ub;
  ua.f = a; ub.f = b;
  uint32_t x = ua.u + (0x7FFFu + ((ua.u >> 16) & 1u));
  uint32_t y = ub.u + (0x7FFFu + ((ub.u >> 16) & 1u));
  return (x >> 16) | (y & 0xFFFF0000u);
}

// ---------------- gather + cast: xp[r] = bf16(hs[perm[r]]) ----------------
__global__ __launch_bounds__(256)
void gather_cast_kernel(const float* __restrict__ hs, const int* __restrict__ perm,
                        uint32_t* __restrict__ xp) {
  const int r = blockIdx.x;
  const int t = threadIdx.x;
  const int src = perm[r];
  const float4* in = (const float4*)(hs + (size_t)src * H_DIM);
  float4 v = in[t];
  uint2 o;
  o.x = pack2_bf16(v.x, v.y);
  o.y = pack2_bf16(v.z, v.w);
  ((uint2*)(xp + (size_t)r * (H_DIM / 2)))[t] = o;
}

// ---------------- grouped GEMM:  C = A(bf16,[E][512][K]) * B(f32,[E][N][K])^T ----------------
// LDS tiles are [128 rows][64 bf16] with XOR chunk swizzle: logical 16B-chunk c of
// row r lives at physical chunk c ^ (r&7).  A: linear gload_lds dest + inverse-
// swizzled global source (m173).  B: swizzled ds_write.  Reads apply the same XOR.
// EPI1: Hout[e][row][col] = bf16(gelu(acc + b1))       (GEMM1)
// !EPI1: Oout[perm[grow]][col] = acc + b2   (fp32)     (GEMM2, scatter)
template<bool EPI1, int N, int K, int LOG_NBN>
__global__ __launch_bounds__(256, 2)
void moe_gemm_kernel(const bf16* __restrict__ A, const float* __restrict__ Bw,
                     const float* __restrict__ bias, bf16* __restrict__ Hout,
                     float* __restrict__ Oout, const int* __restrict__ perm) {
  constexpr int BK = 64;
  __shared__ bf16 As[2][128 * BK];
  __shared__ bf16 Bs[2][128 * BK];

  // bijective chunked XCD swizzle (m204): each XCD gets a contiguous logical
  // range so the 4 bm-blocks sharing a B panel land on ONE XCD's L2.
  const int nwg  = gridDim.x;          // multiple of 8
  const int qx   = nwg >> 3;
  const int orig = blockIdx.x;
  const int wg   = (orig & 7) * qx + (orig >> 3);
  const int bm = wg & 3;
  const int bn = (wg >> 2) & ((N / 128) - 1);
  const int e  = wg >> (2 + LOG_NBN);

  const int tid = threadIdx.x;
  const int l  = tid & 63;
  const int w  = tid >> 6;
  const int wr = w >> 1, wc = w & 1;
  const int fr = l & 15, fq = l >> 4;
  const int rx = fr & 7;               // row&7 for all fragment rows

  const bf16*  Ae = A  + (size_t)e * MPE * K + (size_t)bm * 128 * K;
  const float* Be = Bw + (size_t)e * N  * K + (size_t)bn * 128 * K;

  const int srow   = tid >> 3;                     // 0..31 within 32-row slab
  const int schunk = tid & 7;                      // 16B chunk along K
  const int sswzA  = (schunk ^ (srow & 7)) * 8;    // inverse-swizzled A source col
  // B: linear global source, swizzled LDS write offset (elements within slab)
  const int bwoff  = srow * 64 + (schunk ^ (srow & 7)) * 8;

  f32x4 acc[4][4];
#pragma unroll
  for (int m = 0; m < 4; ++m)
#pragma unroll
    for (int n = 0; n < 4; ++n) acc[m][n] = (f32x4){0.f, 0.f, 0.f, 0.f};

  const int nk = K / BK;
  float4 breg[8];

  // ---- prologue: stage kt=0 into buffer 0
#pragma unroll
  for (int i = 0; i < 4; ++i) {
    const bf16* g = Ae + (size_t)(i * 32 + srow) * K + sswzA;
    __builtin_amdgcn_global_load_lds((GLV*)g, (LDSV*)&As[0][(i * 256 + w * 64) * 8], 16, 0, 0);
  }
#pragma unroll
  for (int i = 0; i < 4; ++i) {
    const float* g = Be + (size_t)(i * 32 + srow) * K + schunk * 8;
    breg[2 * i]     = *(const float4*)g;
    breg[2 * i + 1] = *(const float4*)(g + 4);
  }
#pragma unroll
  for (int i = 0; i < 4; ++i) {
    uint4 pk;
    pk.x = pack2_bf16(breg[2 * i].x,     breg[2 * i].y);
    pk.y = pack2_bf16(breg[2 * i].z,     breg[2 * i].w);
    pk.z = pack2_bf16(breg[2 * i + 1].x, breg[2 * i + 1].y);
    pk.w = pack2_bf16(breg[2 * i + 1].z, breg[2 * i + 1].w);
    *(uint4*)&Bs[0][i * 2048 + bwoff] = pk;
  }
  __syncthreads();

  for (int kt = 0; kt < nk; ++kt) {
    const int cur = kt & 1;
    const int nxt = cur ^ 1;
    const bool more = (kt + 1) < nk;

    if (more) {
      const int ko = (kt + 1) * BK;
#pragma unroll
      for (int i = 0; i < 4; ++i) {
        const bf16* g = Ae + (size_t)(i * 32 + srow) * K + ko + sswzA;
        __builtin_amdgcn_global_load_lds((GLV*)g, (LDSV*)&As[nxt][(i * 256 + w * 64) * 8], 16, 0, 0);
      }
#pragma unroll
      for (int i = 0; i < 4; ++i) {
        const float* g = Be + (size_t)(i * 32 + srow) * K + ko + schunk * 8;
        breg[2 * i]     = *(const float4*)g;
        breg[2 * i + 1] = *(const float4*)(g + 4);
      }
    }

    // ---- compute current buffer (reads use the XOR swizzle)
#pragma unroll
    for (int kk = 0; kk < 2; ++kk) {
      const int ch = (kk * 4 + fq) ^ rx;   // physical 16B chunk
      short8 af[4], bfv[4];
#pragma unroll
      for (int m = 0; m < 4; ++m)
        af[m] = *(const short8*)&As[cur][(wr * 64 + m * 16 + fr) * BK + ch * 8];
#pragma unroll
      for (int n = 0; n < 4; ++n)
        bfv[n] = *(const short8*)&Bs[cur][(wc * 64 + n * 16 + fr) * BK + ch * 8];
#pragma unroll
      for (int m = 0; m < 4; ++m)
#pragma unroll
        for (int n = 0; n < 4; ++n)
          acc[m][n] = __builtin_amdgcn_mfma_f32_16x16x32_bf16(af[m], bfv[n], acc[m][n], 0, 0, 0);
    }

    if (more) {
#pragma unroll
      for (int i = 0; i < 4; ++i) {
        uint4 pk;
        pk.x = pack2_bf16(breg[2 * i].x,     breg[2 * i].y);
        pk.y = pack2_bf16(breg[2 * i].z,     breg[2 * i].w);
        pk.z = pack2_bf16(breg[2 * i + 1].x, breg[2 * i + 1].y);
        pk.w = pack2_bf16(breg[2 * i + 1].z, breg[2 * i + 1].w);
        *(uint4*)&Bs[nxt][i * 2048 + bwoff] = pk;
      }
    }
    __syncthreads();
  }

  // ---- epilogue
  float bv[4];
#pragma unroll
  for (int n = 0; n < 4; ++n)
    bv[n] = bias[(size_t)e * N + bn * 128 + wc * 64 + n * 16 + fr];

  if (EPI1) {
    bf16* He = Hout + (size_t)e * MPE * N;
#pragma unroll
    for (int m = 0; m < 4; ++m) {
#pragma unroll
      for (int j = 0; j < 4; ++j) {
        const int row = bm * 128 + wr * 64 + m * 16 + fq * 4 + j;
#pragma unroll
        for (int n = 0; n < 4; ++n) {
          const int col = bn * 128 + wc * 64 + n * 16 + fr;
          float x = acc[m][n][j] + bv[n];
          float g = 0.5f * x * (1.0f + erff(x * 0.70710678118654752f));
          He[(size_t)row * N + col] = __float2bfloat16(g);
        }
      }
    }
  } else {
#pragma unroll
    for (int m = 0; m < 4; ++m) {
#pragma unroll
      for (int j = 0; j < 4; ++j) {
        const int grow = e * MPE + bm * 128 + wr * 64 + m * 16 + fq * 4 + j;
        const int drow = perm[grow];
        float* orow = Oout + (size_t)drow * N;
#pragma unroll
        for (int n = 0; n < 4; ++n) {
          const int col = bn * 128 + wc * 64 + n * 16 + fr;
          orow[col] = acc[m][n][j] + bv[n];
        }
      }
    }
  }
}

// ---------------- residual + LayerNorm (in place on out) ----------------
__global__ __launch_bounds__(256)
void ln_resid_kernel(float* __restrict__ out, const float* __restrict__ hs,
                     const float* __restrict__ gamma, const float* __restrict__ beta) {
  const int r = blockIdx.x;
  const int t = threadIdx.x;
  float4 o = ((const float4*)(out + (size_t)r * H_DIM))[t];
  float4 h = ((const float4*)(hs  + (size_t)r * H_DIM))[t];
  float v0 = o.x + h.x, v1 = o.y + h.y, v2 = o.z + h.z, v3 = o.w + h.w;
  float s  = v0 + v1 + v2 + v3;
  float sq = v0 * v0 + v1 * v1 + v2 * v2 + v3 * v3;
#pragma unroll
  for (int off = 32; off > 0; off >>= 1) {
    s  += __shfl_down(s, off);
    sq += __shfl_down(sq, off);
  }
  __shared__ float ss[4], ssq[4];
  const int wv = t >> 6;
  if ((t & 63) == 0) { ss[wv] = s; ssq[wv] = sq; }
  __syncthreads();
  s  = ss[0] + ss[1] + ss[2] + ss[3];
  sq = ssq[0] + ssq[1] + ssq[2] + ssq[3];
  const float mu  = s * (1.0f / (float)H_DIM);
  const float var = sq * (1.0f / (float)H_DIM) - mu * mu;
  const float rs  = rsqrtf(var + 1e-12f);
  float4 g = ((const float4*)gamma)[t];
  float4 b = ((const float4*)beta)[t];
  float4 rr;
  rr.x = (v0 - mu) * rs * g.x + b.x;
  rr.y = (v1 - mu) * rs * g.y + b.y;
  rr.z = (v2 - mu) * rs * g.z + b.z;
  rr.w = (v3 - mu) * rs * g.w + b.w;
  ((float4*)(out + (size_t)r * H_DIM))[t] = rr;
}

extern "C" void kernel_launch(void* const* d_in, const int* in_sizes, int n_in,
                              void* d_out, int out_size, void* d_ws, size_t ws_size,
                              hipStream_t stream) {
  const float* hs    = (const float*)d_in[0];
  const int*   perm  = (const int*)d_in[1];
  const float* w1    = (const float*)d_in[2];
  const float* b1    = (const float*)d_in[3];
  const float* w2    = (const float*)d_in[4];
  const float* b2    = (const float*)d_in[5];
  const float* gamma = (const float*)d_in[6];
  const float* beta  = (const float*)d_in[7];
  float* out = (float*)d_out;

  // workspace: xp bf16 [T][H] = 16 MB, h bf16 [T][I] = 64 MB
  bf16* xp   = (bf16*)d_ws;
  bf16* hbuf = (bf16*)((char*)d_ws + (size_t)T_NUM * H_DIM * sizeof(bf16));

  gather_cast_kernel<<<T_NUM, 256, 0, stream>>>(hs, perm, (uint32_t*)xp);

  // GEMM1: M=512/expert, N=4096, K=1024 -> nwg = 4*32*16 = 2048
  moe_gemm_kernel<true, I_DIM, H_DIM, 5><<<2048, 256, 0, stream>>>(xp, w1, b1, hbuf, nullptr, nullptr);

  // GEMM2: M=512/expert, N=1024, K=4096 -> nwg = 4*8*16 = 512
  moe_gemm_kernel<false, H_DIM, I_DIM, 3><<<512, 256, 0, stream>>>(hbuf, w2, b2, nullptr, out, perm);

  ln_resid_kernel<<<T_NUM, 256, 0, stream>>>(out, hs, gamma, beta);
}

// Round 3
// 362.688 us; speedup vs baseline: 1.4448x; 1.0214x over previous
//
#include <hip/hip_runtime.h>
#include <hip/hip_bf16.h>
#include <stdint.h>

#define E_NUM 16
#define T_NUM 8192
#define H_DIM 1024
#define I_DIM 4096
#define MPE   512   // tokens per expert

typedef __attribute__((ext_vector_type(8))) short short8;
typedef __attribute__((ext_vector_type(4))) float f32x4;
using bf16 = __hip_bfloat16;

typedef const __attribute__((address_space(1))) void GLV;
typedef __attribute__((address_space(3))) void LDSV;

// round-to-nearest-even f32 -> bf16, packed pair into one u32
__device__ __forceinline__ uint32_t pack2_bf16(float a, float b) {
  union { float f; uint32_t u; } ua, ub;
  ua.f = a; ub.f = b;
  uint32_t x = ua.u + (0x7FFFu + ((ua.u >> 16) & 1u));
  uint32_t y = ub.u + (0x7FFFu + ((ub.u >> 16) & 1u));
  return (x >> 16) | (y & 0xFFFF0000u);
}

// 8 f32 -> short8 of bf16 (RNE, via v_cvt_pk_bf16_f32)
__device__ __forceinline__ short8 cvt8(f32x4 a, f32x4 b) {
  union { short8 s; __hip_bfloat162 h[4]; } r;
  r.h[0] = __float22bfloat162_rn({a[0], a[1]});
  r.h[1] = __float22bfloat162_rn({a[2], a[3]});
  r.h[2] = __float22bfloat162_rn({b[0], b[1]});
  r.h[3] = __float22bfloat162_rn({b[2], b[3]});
  return r.s;
}

// ---------------- gather + cast: xp[r] = bf16(hs[perm[r]]) ----------------
__global__ __launch_bounds__(256)
void gather_cast_kernel(const float* __restrict__ hs, const int* __restrict__ perm,
                        uint32_t* __restrict__ xp) {
  const int r = blockIdx.x;
  const int t = threadIdx.x;
  const int src = perm[r];
  const float4* in = (const float4*)(hs + (size_t)src * H_DIM);
  float4 v = in[t];
  uint2 o;
  o.x = pack2_bf16(v.x, v.y);
  o.y = pack2_bf16(v.z, v.w);
  ((uint2*)(xp + (size_t)r * (H_DIM / 2)))[t] = o;
}

// ---------------- grouped GEMM, deep pipeline ----------------
// C = A(bf16,[E][512][K]) * B(f32,[E][N][K])^T, BM=256, BN in {256,128}, BK=32.
// 512 threads = 8 waves (2M x 4N); per-wave 128 x (BN/4); acc 8 x (BN/64).
// Triple-buffered LDS; A bf16 via global_load_lds (linear, 64B rows -> conflict
// free); B fp32 via global_load_lds with XOR chunk swizzle c^(col&7) applied to
// the pre-swizzled GLOBAL source (m173), same XOR on ds_read; cvt_pk on read.
// Counted vmcnt (never 0 in steady state) + raw s_barrier: tile t computes
// while t+1 is landed and t+2 is in flight.
template<bool EPI1, int BN, int N, int K, int LOG_NBN>
__global__ __launch_bounds__(512, 2)
void moe_gemm_kernel(const bf16* __restrict__ A, const float* __restrict__ Bw,
                     const float* __restrict__ bias, bf16* __restrict__ Hout,
                     float* __restrict__ Oout, const int* __restrict__ perm) {
  constexpr int NREP = BN / 64;     // B frags per wave (4 or 2)
  constexpr int NK   = K / 32;      // K-tiles
  __shared__ char AsB[3 * 16384];         // 3 x 256x32 bf16
  __shared__ char BsB[3 * BN * 128];      // 3 x BNx32 f32

  // bijective chunked XCD swizzle (m204); nwg % 8 == 0 for both GEMMs
  const int nwg  = gridDim.x;
  const int qx   = nwg >> 3;
  const int orig = blockIdx.x;
  const int wg   = (orig & 7) * qx + (orig >> 3);
  const int bm = wg & 1;
  const int bn = (wg >> 1) & ((1 << LOG_NBN) - 1);
  const int e  = wg >> (1 + LOG_NBN);

  const int tid = threadIdx.x;
  const int l  = tid & 63;
  const int w  = tid >> 6;          // 0..7
  const int wr = w >> 2, wc = w & 3;
  const int fr = l & 15, fq = l >> 4;

  const bf16*  Ae = A  + ((size_t)e * MPE + bm * 256) * K;
  const float* Be = Bw + ((size_t)e * N + (size_t)bn * BN) * K;

  // stage one K-tile (A: 2 ops, B: NREP ops) into buffer `buf`
  auto stage = [&](int buf, int kt) {
#pragma unroll
    for (int i = 0; i < 2; ++i) {
      const bf16* g = Ae + (size_t)(i * 128 + (tid >> 2)) * K + kt * 32 + (tid & 3) * 8;
      __builtin_amdgcn_global_load_lds((GLV*)g, (LDSV*)(AsB + buf * 16384 + i * 8192 + tid * 16), 16, 0, 0);
    }
#pragma unroll
    for (int j = 0; j < NREP; ++j) {
      const int col = j * 64 + (tid >> 3);
      const int cs  = (tid & 7) ^ (col & 7);        // inverse-swizzled source chunk
      const float* g = Be + (size_t)col * K + kt * 32 + cs * 4;
      __builtin_amdgcn_global_load_lds((GLV*)g, (LDSV*)(BsB + buf * (BN * 128) + j * 8192 + tid * 16), 16, 0, 0);
    }
  };

  f32x4 acc[8][NREP];
#pragma unroll
  for (int m = 0; m < 8; ++m)
#pragma unroll
    for (int n = 0; n < NREP; ++n) acc[m][n] = (f32x4){0.f, 0.f, 0.f, 0.f};

  // ---- prologue: tiles 0 and 1 staged; wait tile 0; barrier
  stage(0, 0);
  stage(1, 1);
  if constexpr (BN == 256) asm volatile("s_waitcnt vmcnt(6)" ::: "memory");
  else                     asm volatile("s_waitcnt vmcnt(4)" ::: "memory");
  __builtin_amdgcn_sched_barrier(0);
  __builtin_amdgcn_s_barrier();
  __builtin_amdgcn_sched_barrier(0);

  int bufc = 0;
  for (int t = 0; t < NK; ++t) {
    const int bufn = (bufc >= 1) ? bufc - 1 : bufc + 2;   // (bufc+2)%3
    if (t + 2 < NK) stage(bufn, t + 2);

    const char* Ab = AsB + bufc * 16384;
    const char* Bb = BsB + bufc * (BN * 128);

    short8 a8[8];
#pragma unroll
    for (int m = 0; m < 8; ++m)
      a8[m] = *(const short8*)(Ab + (wr * 128 + m * 16 + fr) * 64 + fq * 16);

    short8 b8[NREP];
#pragma unroll
    for (int n = 0; n < NREP; ++n) {
      const int col = wc * (BN / 4) + n * 16 + fr;
      const f32x4 x0 = *(const f32x4*)(Bb + col * 128 + (((2 * fq)    ^ (col & 7)) * 16));
      const f32x4 x1 = *(const f32x4*)(Bb + col * 128 + (((2 * fq + 1) ^ (col & 7)) * 16));
      b8[n] = cvt8(x0, x1);
    }

    __builtin_amdgcn_s_setprio(1);
#pragma unroll
    for (int m = 0; m < 8; ++m)
#pragma unroll
      for (int n = 0; n < NREP; ++n)
        acc[m][n] = __builtin_amdgcn_mfma_f32_16x16x32_bf16(a8[m], b8[n], acc[m][n], 0, 0, 0);
    __builtin_amdgcn_s_setprio(0);

    // counted drain: tile t+1 must be landed; t+2's ops stay in flight
    if (t + 2 < NK) {
      if constexpr (BN == 256) asm volatile("s_waitcnt vmcnt(6)" ::: "memory");
      else                     asm volatile("s_waitcnt vmcnt(4)" ::: "memory");
    } else if (t + 1 < NK) {
      asm volatile("s_waitcnt vmcnt(0)" ::: "memory");
    }
    __builtin_amdgcn_sched_barrier(0);
    __builtin_amdgcn_s_barrier();
    __builtin_amdgcn_sched_barrier(0);

    bufc = (bufc == 2) ? 0 : bufc + 1;
  }

  // ---- epilogue
  float bv[NREP];
#pragma unroll
  for (int n = 0; n < NREP; ++n)
    bv[n] = bias[(size_t)e * N + bn * BN + wc * (BN / 4) + n * 16 + fr];

  if (EPI1) {
    bf16* He = Hout + (size_t)e * MPE * N;
#pragma unroll
    for (int m = 0; m < 8; ++m) {
#pragma unroll
      for (int j = 0; j < 4; ++j) {
        const int row = bm * 256 + wr * 128 + m * 16 + fq * 4 + j;
#pragma unroll
        for (int n = 0; n < NREP; ++n) {
          const int col = bn * BN + wc * (BN / 4) + n * 16 + fr;
          float x = acc[m][n][j] + bv[n];
          float g = 0.5f * x * (1.0f + erff(x * 0.70710678118654752f));
          He[(size_t)row * N + col] = __float2bfloat16(g);
        }
      }
    }
  } else {
#pragma unroll
    for (int m = 0; m < 8; ++m) {
#pragma unroll
      for (int j = 0; j < 4; ++j) {
        const int grow = e * MPE + bm * 256 + wr * 128 + m * 16 + fq * 4 + j;
        const int drow = perm[grow];
        float* orow = Oout + (size_t)drow * N;
#pragma unroll
        for (int n = 0; n < NREP; ++n) {
          const int col = bn * BN + wc * (BN / 4) + n * 16 + fr;
          orow[col] = acc[m][n][j] + bv[n];
        }
      }
    }
  }
}

// ---------------- residual + LayerNorm (in place on out) ----------------
__global__ __launch_bounds__(256)
void ln_resid_kernel(float* __restrict__ out, const float* __restrict__ hs,
                     const float* __restrict__ gamma, const float* __restrict__ beta) {
  const int r = blockIdx.x;
  const int t = threadIdx.x;
  float4 o = ((const float4*)(out + (size_t)r * H_DIM))[t];
  float4 h = ((const float4*)(hs  + (size_t)r * H_DIM))[t];
  float v0 = o.x + h.x, v1 = o.y + h.y, v2 = o.z + h.z, v3 = o.w + h.w;
  float s  = v0 + v1 + v2 + v3;
  float sq = v0 * v0 + v1 * v1 + v2 * v2 + v3 * v3;
#pragma unroll
  for (int off = 32; off > 0; off >>= 1) {
    s  += __shfl_down(s, off);
    sq += __shfl_down(sq, off);
  }
  __shared__ float ss[4], ssq[4];
  const int wv = t >> 6;
  if ((t & 63) == 0) { ss[wv] = s; ssq[wv] = sq; }
  __syncthreads();
  s  = ss[0] + ss[1] + ss[2] + ss[3];
  sq = ssq[0] + ssq[1] + ssq[2] + ssq[3];
  const float mu  = s * (1.0f / (float)H_DIM);
  const float var = sq * (1.0f / (float)H_DIM) - mu * mu;
  const float rs  = rsqrtf(var + 1e-12f);
  float4 g = ((const float4*)gamma)[t];
  float4 b = ((const float4*)beta)[t];
  float4 rr;
  rr.x = (v0 - mu) * rs * g.x + b.x;
  rr.y = (v1 - mu) * rs * g.y + b.y;
  rr.z = (v2 - mu) * rs * g.z + b.z;
  rr.w = (v3 - mu) * rs * g.w + b.w;
  ((float4*)(out + (size_t)r * H_DIM))[t] = rr;
}

extern "C" void kernel_launch(void* const* d_in, const int* in_sizes, int n_in,
                              void* d_out, int out_size, void* d_ws, size_t ws_size,
                              hipStream_t stream) {
  const float* hs    = (const float*)d_in[0];
  const int*   perm  = (const int*)d_in[1];
  const float* w1    = (const float*)d_in[2];
  const float* b1    = (const float*)d_in[3];
  const float* w2    = (const float*)d_in[4];
  const float* b2    = (const float*)d_in[5];
  const float* gamma = (const float*)d_in[6];
  const float* beta  = (const float*)d_in[7];
  float* out = (float*)d_out;

  // workspace: xp bf16 [T][H] = 16 MB, h bf16 [T][I] = 64 MB
  bf16* xp   = (bf16*)d_ws;
  bf16* hbuf = (bf16*)((char*)d_ws + (size_t)T_NUM * H_DIM * sizeof(bf16));

  gather_cast_kernel<<<T_NUM, 256, 0, stream>>>(hs, perm, (uint32_t*)xp);

  // GEMM1: BM=256, BN=256 -> nwg = 2 * 16 * 16 = 512
  moe_gemm_kernel<true, 256, I_DIM, H_DIM, 4><<<512, 512, 0, stream>>>(xp, w1, b1, hbuf, nullptr, nullptr);

  // GEMM2: BM=256, BN=128 -> nwg = 2 * 8 * 16 = 256 (full CU coverage)
  moe_gemm_kernel<false, 128, H_DIM, I_DIM, 3><<<256, 512, 0, stream>>>(hbuf, w2, b2, nullptr, out, perm);

  ln_resid_kernel<<<T_NUM, 256, 0, stream>>>(out, hs, gamma, beta);
}